// Round 1
// baseline (463.942 us; speedup 1.0000x reference)
//
#include <hip/hip_runtime.h>
#include <hip/hip_bf16.h>
#include <math.h>

// Problem: b=4, t=2048, c=64, mw=64, modes=16, SCALE=1/4096.
// Reference keeps only 16 low rfft bins -> whole pipeline is dense linear algebra:
//   Stage A: Y[j,dh] = sum_t W[j,t] x[t,dh]   (32x2048 DFT basis, radix-2 folded)
//   Stage B: per (b,h) complex 16x16 attention w/ complex tanh
//   Stage C: out[t,dh] = sum_j B[t,j] G[j,dh] (scaled inverse basis)

#define B_DIM 4
#define T_DIM 2048
#define DH 4096           // c*mw = 64*64
#define MODES 16
#define CHUNKS 8
#define TPC (1024 / CHUNKS)   // t-pairs per chunk = 128

// ---------------- twiddle tables ----------------
__global__ void init_tables(float* __restrict__ Wt, float* __restrict__ Bt) {
    int i = blockIdx.x * 256 + threadIdx.x;
    const float TWO_PI = 6.2831853071795864769f;
    if (i < 1024 * 32) {
        int t = i >> 5, j = i & 31, m = j & 15;
        int ph = (m * t) & 2047;                 // exact phase reduction
        float ang = TWO_PI * (float)ph / 2048.0f;
        Wt[i] = (j < 16) ? cosf(ang) : sinf(ang);
    }
    int i2 = i - 1024 * 32;
    if (i2 >= 0 && i2 < 2048 * 32) {
        int t = i2 >> 5, j = i2 & 31, m = j & 15;
        int ph = (m * t) & 2047;
        float ang = TWO_PI * (float)ph / 2048.0f;
        const float S2 = 1.0f / (4096.0f * 2048.0f);   // SCALE / n
        float coef = (m == 0 ? 1.0f : 2.0f) * S2;
        float val;
        if (j < 16)      val = coef * cosf(ang);
        else if (m == 0) val = 0.0f;                   // Im of DC bin ignored by irfft
        else             val = -coef * sinf(ang);
        Bt[i2] = val;
    }
}

// ---------------- stage A: forward 16-mode DFT (chunked partials) ----------------
// P[tensor][b][chunk][j][dh], j: 0..15 Re, 16..31 Im
__global__ __launch_bounds__(256) void stageA(
        const float* __restrict__ q, const float* __restrict__ k,
        const float* __restrict__ v, const float* __restrict__ Wt,
        float* __restrict__ P) {
    int tid = threadIdx.x;
    int dh  = blockIdx.x * 256 + tid;
    int c   = blockIdx.y;             // chunk
    int tz  = blockIdx.z;             // tensor*4 + b
    int tensor = tz >> 2;
    int b      = tz & 3;
    const float* src = (tensor == 0 ? q : tensor == 1 ? k : v)
                       + (size_t)b * T_DIM * DH;
    float accC[16], accS[16];
    #pragma unroll
    for (int m = 0; m < 16; m++) { accC[m] = 0.f; accS[m] = 0.f; }

    int t0 = c * TPC;
    const float* s0 = src + (size_t)t0 * DH + dh;
    const float* s1 = s0 + (size_t)1024 * DH;
    const float* wr0 = Wt + (size_t)t0 * 32;

    #pragma unroll 2
    for (int tl = 0; tl < TPC; tl++) {
        float x0 = s0[(size_t)tl * DH];
        float x1 = s1[(size_t)tl * DH];
        float u = x0 + x1;            // even modes (radix-2 fold)
        float w = x0 - x1;            // odd modes
        const float* wr = wr0 + tl * 32;   // uniform address -> s_load
        #pragma unroll
        for (int m = 0; m < 16; m++) {
            float sm = (m & 1) ? w : u;
            accC[m] = fmaf(wr[m],      sm, accC[m]);
            accS[m] = fmaf(wr[16 + m], sm, accS[m]);
        }
    }
    float* pp = P + (((size_t)tz * CHUNKS + c) * 32) * DH + dh;
    #pragma unroll
    for (int m = 0; m < 16; m++) {
        pp[(size_t)m * DH]        = accC[m];    // Re
        pp[(size_t)(16 + m) * DH] = -accS[m];   // Im = -sum x sin
    }
}

// ---------------- stage A2: reduce chunk partials ----------------
// Y[tensor][b][j][dh] = sum_c P[...]
__global__ __launch_bounds__(256) void reduceP(const float* __restrict__ P,
                                               float* __restrict__ Y) {
    size_t i   = (size_t)blockIdx.x * 256 + threadIdx.x;  // 3*4*32*4096 total
    size_t tzj = i >> 12;          // tz*32 + j
    size_t dh  = i & 4095;
    size_t tz  = tzj >> 5;
    size_t j   = tzj & 31;
    const float* p = P + ((tz * CHUNKS) * 32 + j) * DH + dh;
    float s = 0.f;
    #pragma unroll
    for (int cc = 0; cc < CHUNKS; cc++) s += p[(size_t)cc * 32 * DH];
    Y[i] = s;
}

// ---------------- stage B: complex mode-space attention ----------------
// G[b][j][dh], j: 0..15 Re(qkv), 16..31 Im(qkv)
__global__ __launch_bounds__(256) void stageB(const float* __restrict__ Y,
                                              float* __restrict__ G) {
    __shared__ float qf[64 * 33];   // [d][j], +1 pad style (stride 33)
    __shared__ float kf[64 * 33];
    __shared__ float vf[64 * 33];
    __shared__ float qkr[16 * 17];
    __shared__ float qki[16 * 17];

    int tid = threadIdx.x;
    int bh  = blockIdx.x;
    int b   = bh >> 6;
    int h   = bh & 63;

    #pragma unroll
    for (int tensor = 0; tensor < 3; tensor++) {
        float* dst = (tensor == 0 ? qf : tensor == 1 ? kf : vf);
        const float* yp = Y + ((size_t)(tensor * 4 + b) * 32) * DH + h;
        #pragma unroll
        for (int it = 0; it < 8; it++) {
            int p = it * 256 + tid;
            int d = p & 63, j = p >> 6;
            dst[d * 33 + j] = yp[(size_t)j * DH + d * 64];
        }
    }
    __syncthreads();

    // qk[x,y] = sum_d qf[d,x] * kf[d,y]  (complex, no conj)
    int x = tid >> 4, y = tid & 15;
    float ar = 0.f, ai = 0.f;
    #pragma unroll 4
    for (int d = 0; d < 64; d++) {
        float qr = qf[d * 33 + x],      qi = qf[d * 33 + 16 + x];
        float kr = kf[d * 33 + y],      ki = kf[d * 33 + 16 + y];
        ar += qr * kr - qi * ki;
        ai += qr * ki + qi * kr;
    }
    // stable complex tanh: (sinh 2a + i sin 2b) / (cosh 2a + cos 2b)
    float re, im;
    float a2 = 2.f * ar, b2 = 2.f * ai;
    if (fabsf(a2) < 80.f) {
        float den = coshf(a2) + cosf(b2);
        re = sinhf(a2) / den;
        im = sinf(b2) / den;
    } else {
        re = copysignf(1.f, ar);
        im = 0.f;
    }
    qkr[x * 17 + y] = re;
    qki[x * 17 + y] = im;
    __syncthreads();

    // qkv[d,x] = sum_y qk[x,y] * vf[d,y]
    int xx = tid & 15, db = tid >> 4;
    #pragma unroll
    for (int i = 0; i < 4; i++) {
        int d = db + i * 16;
        float cr = 0.f, ci = 0.f;
        #pragma unroll
        for (int yy = 0; yy < 16; yy++) {
            float tr = qkr[xx * 17 + yy], ti = qki[xx * 17 + yy];
            float vr = vf[d * 33 + yy],   vi = vf[d * 33 + 16 + yy];
            cr += tr * vr - ti * vi;
            ci += tr * vi + ti * vr;
        }
        G[((size_t)b * 32 + xx) * DH + d * 64 + h]      = cr;
        G[((size_t)b * 32 + 16 + xx) * DH + d * 64 + h] = ci;
    }
}

// ---------------- stage C: 16-mode inverse transform ----------------
__global__ __launch_bounds__(256) void stageC(const float* __restrict__ G,
                                              const float* __restrict__ Bt,
                                              float* __restrict__ out) {
    int tid   = threadIdx.x;
    int dh    = blockIdx.x * 256 + tid;
    int ttile = blockIdx.y;        // 16 tiles of 128 t
    int b     = blockIdx.z;

    float g[32];
    const float* gp = G + (size_t)b * 32 * DH + dh;
    #pragma unroll
    for (int j = 0; j < 32; j++) g[j] = gp[(size_t)j * DH];

    float* op = out + ((size_t)b * T_DIM + (size_t)ttile * 128) * DH + dh;
    const float* bp = Bt + (size_t)ttile * 128 * 32;   // uniform -> s_load
    for (int tl = 0; tl < 128; tl++) {
        float acc = 0.f;
        #pragma unroll
        for (int j = 0; j < 32; j++) acc = fmaf(bp[tl * 32 + j], g[j], acc);
        op[(size_t)tl * DH] = acc;
    }
}

extern "C" void kernel_launch(void* const* d_in, const int* in_sizes, int n_in,
                              void* d_out, int out_size, void* d_ws, size_t ws_size,
                              hipStream_t stream) {
    const float* q = (const float*)d_in[0];
    const float* k = (const float*)d_in[1];
    const float* v = (const float*)d_in[2];
    float* out = (float*)d_out;

    char* ws = (char*)d_ws;
    float* Wt = (float*)ws;                                   //   131072 B
    float* Bt = (float*)(ws + 131072);                        //   262144 B
    float* P  = (float*)(ws + 131072 + 262144);               // 50331648 B
    float* Y  = (float*)(ws + 131072 + 262144 + 50331648);    //  6291456 B
    float* G  = (float*)(ws + 131072 + 262144 + 50331648 + 6291456); // 2097152 B

    init_tables<<<384, 256, 0, stream>>>(Wt, Bt);
    stageA<<<dim3(16, CHUNKS, 12), 256, 0, stream>>>(q, k, v, Wt, P);
    reduceP<<<6144, 256, 0, stream>>>(P, Y);
    stageB<<<256, 256, 0, stream>>>(Y, G);
    stageC<<<dim3(16, 16, 4), 256, 0, stream>>>(G, Bt, out);
}

// Round 2
// 451.673 us; speedup vs baseline: 1.0272x; 1.0272x over previous
//
#include <hip/hip_runtime.h>
#include <hip/hip_bf16.h>
#include <math.h>

// FEAf lowpass: b=4, t=2048, c=64, mw=64, modes=16, SCALE=1/4096.
// Stage A: 16-mode DFT over t (radix-4 folded), float2 lanes, LDS twiddles.
// reduceP: sum chunk partials.
// Stage B: per (b,h) complex 16x16 attention w/ complex tanh.
// Stage C: 16-mode inverse (radix-2 Hermitian over t), LDS basis tile.

#define T_DIM 2048
#define DH 4096           // c*mw
#define DH2 2048          // float2 view
#define CH 8              // stageA chunks over t' in [0,512)
#define TPCH 64           // t' per chunk = 512/CH
#define TT 32             // stageC t-tile (over t in [0,1024))

// ---------------- twiddle tables ----------------
// WA[t'][2m]=cos(2pi m t'/2048), WA[t'][2m+1]=sin(...)           (t' in [0,512))
// Bt2[t][2m]=coef_m cos(2pi m t/2048), [2m+1]=-coef_m sin(...)   (t in [0,1024))
//   coef_m = (m==0?1:2) * SCALE/2048; sin entry for m==0 is 0.
__global__ void init_tables(float* __restrict__ WA, float* __restrict__ Bt2) {
    int i = blockIdx.x * 256 + threadIdx.x;
    const float TWO_PI = 6.2831853071795864769f;
    if (i < 512 * 32) {
        int t = i >> 5, r = i & 31, m = r >> 1;
        int ph = (m * t) & 2047;
        float ang = TWO_PI * (float)ph * (1.0f / 2048.0f);
        WA[i] = (r & 1) ? sinf(ang) : cosf(ang);
    }
    int i2 = i - 512 * 32;
    if (i2 >= 0 && i2 < 1024 * 32) {
        int t = i2 >> 5, r = i2 & 31, m = r >> 1;
        int ph = (m * t) & 2047;
        float ang = TWO_PI * (float)ph * (1.0f / 2048.0f);
        const float S2 = 1.0f / (4096.0f * 2048.0f);
        float coef = (m == 0 ? 1.0f : 2.0f) * S2;
        float val;
        if (!(r & 1)) val = coef * cosf(ang);
        else          val = (m == 0) ? 0.0f : -coef * sinf(ang);
        Bt2[i2] = val;
    }
}

// ---------------- stage A ----------------
// P[tz][chunk][j][dh]; j: 0..15 Re, 16..31 Im. tz = tensor*4 + b.
__global__ __launch_bounds__(256) void stageA(
        const float* __restrict__ q, const float* __restrict__ k,
        const float* __restrict__ v, const float* __restrict__ WA,
        float* __restrict__ P) {
    __shared__ float w[TPCH * 32];   // 8 KB twiddle tile
    int tid = threadIdx.x;
    int c   = blockIdx.y;
    int tz  = blockIdx.z;
    int tensor = tz >> 2, b = tz & 3;

    #pragma unroll
    for (int it = 0; it < TPCH * 32 / 256; it++)
        w[it * 256 + tid] = WA[c * (TPCH * 32) + it * 256 + tid];
    __syncthreads();

    int dh2 = blockIdx.x * 256 + tid;    // float2 index into DH
    const float* srcf = (tensor == 0 ? q : tensor == 1 ? k : v)
                        + (size_t)b * T_DIM * DH;
    const float2* p0 = (const float2*)srcf + (size_t)(c * TPCH) * DH2 + dh2;

    float2 accR[16], accI[16];
    #pragma unroll
    for (int m = 0; m < 16; m++) {
        accR[m] = make_float2(0.f, 0.f);
        accI[m] = make_float2(0.f, 0.f);
    }

    #pragma unroll 2
    for (int tl = 0; tl < TPCH; tl++) {
        float2 x0 = p0[(size_t)tl * DH2];
        float2 x1 = p0[(size_t)(tl + 512) * DH2];
        float2 x2 = p0[(size_t)(tl + 1024) * DH2];
        float2 x3 = p0[(size_t)(tl + 1536) * DH2];
        float2 u0 = make_float2(x0.x + x2.x, x0.y + x2.y);
        float2 u1 = make_float2(x1.x + x3.x, x1.y + x3.y);
        float2 d0 = make_float2(x0.x - x2.x, x0.y - x2.y);
        float2 d1 = make_float2(x1.x - x3.x, x1.y - x3.y);
        float2 e  = make_float2(u0.x + u1.x, u0.y + u1.y);
        float2 f  = make_float2(u0.x - u1.x, u0.y - u1.y);
        const float* ww = &w[tl * 32];
        #pragma unroll
        for (int m = 0; m < 16; m++) {
            float cm = ww[2 * m], sm = ww[2 * m + 1];
            if ((m & 3) == 0) {
                accR[m].x = fmaf(cm, e.x, accR[m].x);
                accR[m].y = fmaf(cm, e.y, accR[m].y);
                accI[m].x = fmaf(-sm, e.x, accI[m].x);
                accI[m].y = fmaf(-sm, e.y, accI[m].y);
            } else if ((m & 3) == 2) {
                accR[m].x = fmaf(cm, f.x, accR[m].x);
                accR[m].y = fmaf(cm, f.y, accR[m].y);
                accI[m].x = fmaf(-sm, f.x, accI[m].x);
                accI[m].y = fmaf(-sm, f.y, accI[m].y);
            } else if ((m & 3) == 1) {
                // (c - i s)(d0 - i d1): Re = c d0 - s d1; Im = -(s d0 + c d1)
                accR[m].x = fmaf(cm, d0.x, fmaf(-sm, d1.x, accR[m].x));
                accR[m].y = fmaf(cm, d0.y, fmaf(-sm, d1.y, accR[m].y));
                accI[m].x = fmaf(-sm, d0.x, fmaf(-cm, d1.x, accI[m].x));
                accI[m].y = fmaf(-sm, d0.y, fmaf(-cm, d1.y, accI[m].y));
            } else {
                // (c - i s)(d0 + i d1): Re = c d0 + s d1; Im = c d1 - s d0
                accR[m].x = fmaf(cm, d0.x, fmaf(sm, d1.x, accR[m].x));
                accR[m].y = fmaf(cm, d0.y, fmaf(sm, d1.y, accR[m].y));
                accI[m].x = fmaf(-sm, d0.x, fmaf(cm, d1.x, accI[m].x));
                accI[m].y = fmaf(-sm, d0.y, fmaf(cm, d1.y, accI[m].y));
            }
        }
    }
    float2* pp = (float2*)P + (((size_t)tz * CH + c) * 32) * DH2 + dh2;
    #pragma unroll
    for (int m = 0; m < 16; m++) {
        pp[(size_t)m * DH2]        = accR[m];
        pp[(size_t)(16 + m) * DH2] = accI[m];
    }
}

// ---------------- reduce chunk partials: Y[tz][j][dh] ----------------
__global__ __launch_bounds__(256) void reduceP(const float4* __restrict__ P,
                                               float4* __restrict__ Y) {
    size_t i   = (size_t)blockIdx.x * 256 + threadIdx.x;  // 12*32*1024
    size_t tzj = i >> 10;
    size_t dh4 = i & 1023;
    size_t tz  = tzj >> 5;
    size_t j   = tzj & 31;
    const float4* p = P + ((tz * CH) * 32 + j) * 1024 + dh4;
    float4 s = make_float4(0.f, 0.f, 0.f, 0.f);
    #pragma unroll
    for (int cc = 0; cc < CH; cc++) {
        float4 t = p[(size_t)cc * 32 * 1024];
        s.x += t.x; s.y += t.y; s.z += t.z; s.w += t.w;
    }
    Y[i] = s;
}

// ---------------- stage B: complex mode-space attention ----------------
// G[b][j][dh], j: 0..15 Re(qkv), 16..31 Im(qkv)
__global__ __launch_bounds__(256) void stageB(const float* __restrict__ Y,
                                              float* __restrict__ G) {
    __shared__ float qf[64 * 33];
    __shared__ float kf[64 * 33];
    __shared__ float vf[64 * 33];
    __shared__ float qkr[16 * 17];
    __shared__ float qki[16 * 17];

    int tid = threadIdx.x;
    int bh  = blockIdx.x;
    int b   = bh >> 6;
    int h   = bh & 63;

    #pragma unroll
    for (int tensor = 0; tensor < 3; tensor++) {
        float* dst = (tensor == 0 ? qf : tensor == 1 ? kf : vf);
        const float* yp = Y + ((size_t)(tensor * 4 + b) * 32) * DH + h;
        #pragma unroll
        for (int it = 0; it < 8; it++) {
            int p = it * 256 + tid;
            int d = p & 63, j = p >> 6;
            dst[d * 33 + j] = yp[(size_t)j * DH + d * 64];
        }
    }
    __syncthreads();

    int x = tid >> 4, y = tid & 15;
    float ar = 0.f, ai = 0.f;
    #pragma unroll 4
    for (int d = 0; d < 64; d++) {
        float qr = qf[d * 33 + x],      qi = qf[d * 33 + 16 + x];
        float kr = kf[d * 33 + y],      ki = kf[d * 33 + 16 + y];
        ar += qr * kr - qi * ki;
        ai += qr * ki + qi * kr;
    }
    float re, im;
    float a2 = 2.f * ar, b2 = 2.f * ai;
    if (fabsf(a2) < 80.f) {
        float den = coshf(a2) + cosf(b2);
        re = sinhf(a2) / den;
        im = sinf(b2) / den;
    } else {
        re = copysignf(1.f, ar);
        im = 0.f;
    }
    qkr[x * 17 + y] = re;
    qki[x * 17 + y] = im;
    __syncthreads();

    int xx = tid & 15, db = tid >> 4;
    #pragma unroll
    for (int i = 0; i < 4; i++) {
        int d = db + i * 16;
        float cr = 0.f, ci = 0.f;
        #pragma unroll
        for (int yy = 0; yy < 16; yy++) {
            float tr = qkr[xx * 17 + yy], ti = qki[xx * 17 + yy];
            float vr = vf[d * 33 + yy],   vi = vf[d * 33 + 16 + yy];
            cr += tr * vr - ti * vi;
            ci += tr * vi + ti * vr;
        }
        G[((size_t)b * 32 + xx) * DH + d * 64 + h]      = cr;
        G[((size_t)b * 32 + 16 + xx) * DH + d * 64 + h] = ci;
    }
}

// ---------------- stage C: inverse, radix-2 Hermitian over t ----------------
__global__ __launch_bounds__(256) void stageC(const float* __restrict__ G,
                                              const float* __restrict__ Bt2,
                                              float* __restrict__ out) {
    __shared__ float w[TT * 32];   // 4 KB basis tile
    int tid = threadIdx.x;
    int c   = blockIdx.y;          // t-tile over [0,1024), 32 tiles
    int b   = blockIdx.z;

    #pragma unroll
    for (int it = 0; it < TT * 32 / 256; it++)
        w[it * 256 + tid] = Bt2[c * (TT * 32) + it * 256 + tid];
    __syncthreads();

    int dh2 = blockIdx.x * 256 + tid;
    float2 gr[16], gi[16];
    const float2* gp = (const float2*)G + (size_t)b * 32 * DH2 + dh2;
    #pragma unroll
    for (int m = 0; m < 16; m++) {
        gr[m] = gp[(size_t)m * DH2];
        gi[m] = gp[(size_t)(16 + m) * DH2];
    }

    float2* o0 = (float2*)out + ((size_t)b * T_DIM + (size_t)c * TT) * DH2 + dh2;
    #pragma unroll 2
    for (int tl = 0; tl < TT; tl++) {
        const float* ww = &w[tl * 32];
        float2 E = make_float2(0.f, 0.f), O = make_float2(0.f, 0.f);
        #pragma unroll
        for (int m = 0; m < 16; m += 2) {
            E.x = fmaf(ww[2 * m],     gr[m].x, E.x);
            E.x = fmaf(ww[2 * m + 1], gi[m].x, E.x);
            E.y = fmaf(ww[2 * m],     gr[m].y, E.y);
            E.y = fmaf(ww[2 * m + 1], gi[m].y, E.y);
        }
        #pragma unroll
        for (int m = 1; m < 16; m += 2) {
            O.x = fmaf(ww[2 * m],     gr[m].x, O.x);
            O.x = fmaf(ww[2 * m + 1], gi[m].x, O.x);
            O.y = fmaf(ww[2 * m],     gr[m].y, O.y);
            O.y = fmaf(ww[2 * m + 1], gi[m].y, O.y);
        }
        o0[(size_t)tl * DH2] = make_float2(E.x + O.x, E.y + O.y);
        o0[(size_t)(tl + 1024) * DH2] = make_float2(E.x - O.x, E.y - O.y);
    }
}

extern "C" void kernel_launch(void* const* d_in, const int* in_sizes, int n_in,
                              void* d_out, int out_size, void* d_ws, size_t ws_size,
                              hipStream_t stream) {
    const float* q = (const float*)d_in[0];
    const float* k = (const float*)d_in[1];
    const float* v = (const float*)d_in[2];
    float* out = (float*)d_out;

    char* ws = (char*)d_ws;
    float* WA  = (float*)ws;                         //    65536 B
    float* Bt2 = (float*)(ws + 65536);               //   131072 B
    float* P   = (float*)(ws + 65536 + 131072);      // 50331648 B
    float* Y   = (float*)(ws + 65536 + 131072 + 50331648);            // 6 MB
    float* G   = (float*)(ws + 65536 + 131072 + 50331648 + 6291456);  // 2 MB

    init_tables<<<192, 256, 0, stream>>>(WA, Bt2);
    stageA<<<dim3(8, CH, 12), 256, 0, stream>>>(q, k, v, WA, P);
    reduceP<<<1536, 256, 0, stream>>>((const float4*)P, (float4*)Y);
    stageB<<<256, 256, 0, stream>>>(Y, G);
    stageC<<<dim3(8, 32, 4), 256, 0, stream>>>(G, Bt2, out);
}